// Round 6
// baseline (217.177 us; speedup 1.0000x reference)
//
#include <hip/hip_runtime.h>

#define NQ 8
#define BINS 256
#define D 128
#define RPB 32            // rows per block -> grid 256 = minimal B traffic (1 block/CU)
#define THREADS 1024      // 16 waves = 8 bin-windows x 2 row-tiles
#define RSTRIDE 132       // prep staging stride
#define FREG 520          // shorts per frag region (512 + 8 pad -> bank rotation)

typedef short s8v __attribute__((ext_vector_type(8)));   // 8 bf16 in 4 VGPRs
typedef short s4v __attribute__((ext_vector_type(4)));   // 4 bf16 in 2 VGPRs
typedef float f4v __attribute__((ext_vector_type(4)));   // fp32 x4 (subscript = vector extract, no scratch)

static __device__ __forceinline__ unsigned short bf16_rtne(float x) {
    unsigned u = __float_as_uint(x);
    unsigned r = (u + 0x7fffu + ((u >> 16) & 1u)) >> 16;
    return (unsigned short)r;
}
static __device__ __forceinline__ float bf16_to_f(unsigned short h) {
    return __uint_as_float(((unsigned)h) << 16);
}
struct Split3 { short h, m, l; };
static __device__ __forceinline__ Split3 split3(float x) {
    Split3 s;
    unsigned short hb = bf16_rtne(x);
    float r1 = x - bf16_to_f(hb);
    unsigned short mb = bf16_rtne(r1);
    unsigned short lb = bf16_rtne(r1 - bf16_to_f(mb));
    s.h = (short)hb; s.m = (short)mb; s.l = (short)lb;
    return s;
}
static __device__ __forceinline__ unsigned long long u64min(unsigned long long a, unsigned long long b) {
    return a < b ? a : b;
}
static __device__ __forceinline__ unsigned long long shfl_xor_u64(unsigned long long v, int mask) {
    int lo = (int)(unsigned)(v & 0xffffffffull);
    int hi = (int)(unsigned)(v >> 32);
    lo = __shfl_xor(lo, mask, 64);
    hi = __shfl_xor(hi, mask, 64);
    return ((unsigned long long)(unsigned)hi << 32) | (unsigned)lo;
}

// ---- prep: codebooks fp32 -> bf16 3-way split (swizzled [L][kchunk][bin][8]) + ||c||^2 ----
__global__ __launch_bounds__(256) void rvq_prep(
    const float* __restrict__ cb, short* __restrict__ cb_hi,
    short* __restrict__ cb_mid, short* __restrict__ cb_lo,
    float* __restrict__ c2)
{
    __shared__ float st[16 * RSTRIDE];
    const int L = blockIdx.x >> 4;
    const int o = blockIdx.x & 15;
    const int t = threadIdx.x;

    const float4* src = (const float4*)(cb + ((size_t)L * BINS + o * 16) * D);
    #pragma unroll
    for (int i = 0; i < 2; ++i) {
        int f4 = i * 256 + t;
        int row = f4 >> 5, c4 = f4 & 31;
        float4 v = src[f4];
        float* d = &st[row * RSTRIDE + c4 * 4];
        d[0] = v.x; d[1] = v.y; d[2] = v.z; d[3] = v.w;
    }
    __syncthreads();

    const int bin = t >> 4;
    const int kc  = t & 15;
    const float* p = &st[bin * RSTRIDE + kc * 8];
    s8v h8, m8, l8;
    float s = 0.f;
    #pragma unroll
    for (int j = 0; j < 8; ++j) {
        float x = p[j];
        Split3 sp = split3(x);
        h8[j] = sp.h; m8[j] = sp.m; l8[j] = sp.l;
        s = fmaf(x, x, s);
    }
    int idx = (L * 16 + kc) * BINS + (o * 16 + bin);
    ((s8v*)cb_hi)[idx]  = h8;
    ((s8v*)cb_mid)[idx] = m8;
    ((s8v*)cb_lo)[idx]  = l8;
    s += __shfl_xor(s, 1, 64);
    s += __shfl_xor(s, 2, 64);
    s += __shfl_xor(s, 4, 64);
    s += __shfl_xor(s, 8, 64);
    if (kc == 0) c2[L * BINS + o * 16 + bin] = s;
}

// frag store (unchanged image): thread owns (row rr_, kchunk g8, half); region = mt*4 + ks.
static __device__ __forceinline__ void frag_store4(
    const float* rres, short* ah, short* am, short* al, int rr_, int g8, int half)
{
    s4v h4, m4, l4;
    #pragma unroll
    for (int j = 0; j < 4; ++j) {
        Split3 sp = split3(rres[j]);
        h4[j] = sp.h; m4[j] = sp.m; l4[j] = sp.l;
    }
    int q  = g8 & 3;
    int ks = g8 >> 2;
    int mt = rr_ >> 4;
    int r16 = rr_ & 15;
    int idx16 = q * 16 + ((r16 + 4 * q) & 15);
    int off = (mt * 4 + ks) * FREG + idx16 * 8 + half * 4;
    *(s4v*)&ah[off] = h4;
    *(s4v*)&am[off] = m4;
    *(s4v*)&al[off] = l4;
}

// cb loads for one 16-bin half-window; c2 via f4v (no address-taken float4 -> no scratch)
static __device__ __forceinline__ void issue_cb(
    int lv, int base16, int m, int quad,
    const s8v* __restrict__ bhp, const s8v* __restrict__ bmp, const s8v* __restrict__ blp,
    const float* __restrict__ c2p,
    s8v bh[4], s8v bm[4], s8v bl[4], f4v& c2v)
{
    const int bin = base16 + m;
    #pragma unroll
    for (int ks = 0; ks < 4; ++ks) {
        int idx = (lv * 16 + ks * 4 + quad) * BINS + bin;
        bh[ks] = bhp[idx];
        bm[ks] = bmp[idx];
        bl[ks] = blp[idx];
    }
    c2v = *(const f4v*)(c2p + lv * BINS + base16 + quad * 4);
}

// ---- main: 32 rows/block; wave = (window w>>1, row-tile w&1); residual in registers ----
__global__ __launch_bounds__(THREADS, 4) void rvq_kernel(
    const float* __restrict__ hidden,     // [N, D]
    const float* __restrict__ cb_f32,     // [NQ, BINS, D]
    const short* __restrict__ cb_hi,
    const short* __restrict__ cb_mid,
    const short* __restrict__ cb_lo,
    const float* __restrict__ c2p,        // [NQ, BINS]
    float* __restrict__ out_codes,        // [NQ, N] as float
    float* __restrict__ out_quant,        // [N, D]
    int N)
{
    __shared__ __align__(16) short ah[8 * FREG];
    __shared__ __align__(16) short am[8 * FREG];
    __shared__ __align__(16) short al[8 * FREG];
    __shared__ __align__(16) unsigned long long redw[RPB][10];  // 80B rows, 16B-aligned

    const int t = threadIdx.x;
    const int w = t >> 6;                 // wave 0..15
    const int l = t & 63;
    const int quad = l >> 4;
    const int m = l & 15;
    const int win  = w >> 1;              // 0..7: 32-bin window
    const int mt   = w & 1;               // which 16-row tile this wave multiplies
    const int woff = win * 32;
    const int row0 = blockIdx.x * RPB;
    const int rr_  = t >> 5;              // owned row 0..31 (for residual/stores)
    const int gd   = t & 31;
    const int g8   = gd >> 1;             // owned k-chunk 0..15
    const int half = gd & 1;
    const int dbase = g8 * 8 + half * 4;  // first owned dim

    // residual in registers: thread owns row rr_, dims [dbase, dbase+4)
    float rres[4];
    {
        const f4v* hp = (const f4v*)(hidden + (size_t)(row0 + rr_) * D + dbase);
        f4v v = *hp;
        rres[0] = v[0]; rres[1] = v[1]; rres[2] = v[2]; rres[3] = v[3];
    }
    frag_store4(rres, ah, am, al, rr_, g8, half);

    const s8v* bhp = (const s8v*)cb_hi;
    const s8v* bmp = (const s8v*)cb_mid;
    const s8v* blp = (const s8v*)cb_lo;

    s8v bh[4], bm[4], bl[4];
    f4v c2v;
    issue_cb(0, woff, m, quad, bhp, bmp, blp, c2p, bh, bm, bl, c2v);  // B(0, nt0) in flight

    for (int level = 0; level < NQ; ++level) {
        __syncthreads();   // frag stores visible

        // ---- residual fragments for MY row-tile only: 12 b128 ----
        s8v rfh[4], rfm[4], rfl[4];
        {
            const int idx16 = quad * 16 + ((m + 4 * quad) & 15);
            #pragma unroll
            for (int ks = 0; ks < 4; ++ks) {
                int off = (mt * 4 + ks) * FREG + idx16 * 8;
                rfh[ks] = *(const s8v*)&ah[off];
                rfm[ks] = *(const s8v*)&am[off];
                rfl[ks] = *(const s8v*)&al[off];
            }
        }

        unsigned long long best = ~0ull;

        #pragma unroll
        for (int nt = 0; nt < 2; ++nt) {
            // swapped operands: D[bin][row]; same scalar products & chain order as
            // the verified kernel -> bit-identical keys
            f4v a0 = {0.f, 0.f, 0.f, 0.f};   // hh
            f4v a1 = {0.f, 0.f, 0.f, 0.f};   // hm + mh
            f4v a2 = {0.f, 0.f, 0.f, 0.f};   // mm + hl + lh
            __builtin_amdgcn_s_setprio(1);
            #pragma unroll
            for (int ks = 0; ks < 4; ++ks) {
                a0 = __builtin_amdgcn_mfma_f32_16x16x32_bf16(bh[ks], rfh[ks], a0, 0, 0, 0);
                a1 = __builtin_amdgcn_mfma_f32_16x16x32_bf16(bm[ks], rfh[ks], a1, 0, 0, 0);
                a1 = __builtin_amdgcn_mfma_f32_16x16x32_bf16(bh[ks], rfm[ks], a1, 0, 0, 0);
                a2 = __builtin_amdgcn_mfma_f32_16x16x32_bf16(bm[ks], rfm[ks], a2, 0, 0, 0);
                a2 = __builtin_amdgcn_mfma_f32_16x16x32_bf16(bl[ks], rfh[ks], a2, 0, 0, 0);
                a2 = __builtin_amdgcn_mfma_f32_16x16x32_bf16(bh[ks], rfl[ks], a2, 0, 0, 0);
            }
            __builtin_amdgcn_s_setprio(0);
            f4v c2cur = c2v;                      // vector copy (register), no address taken
            const int binbase = woff + nt * 16 + quad * 4;

            // issue next 16-bin half (or next level's first half) after last B use
            if (nt == 0)
                issue_cb(level, woff + 16, m, quad, bhp, bmp, blp, c2p, bh, bm, bl, c2v);
            else if (level + 1 < NQ)
                issue_cb(level + 1, woff, m, quad, bhp, bmp, blp, c2p, bh, bm, bl, c2v);

            #pragma unroll
            for (int i = 0; i < 4; ++i) {
                float dot = a0[i] + (a1[i] + a2[i]);      // same order as verified kernel
                float k = fmaf(-2.f, dot, c2cur[i]);
                unsigned u = __float_as_uint(k);
                u = (u & 0x80000000u) ? ~u : (u | 0x80000000u);
                // pack (key, bin): u64min == min key, ties -> lowest bin
                best = u64min(best, ((unsigned long long)u << 32) | (unsigned)(binbase + i));
            }
        }

        // ---- cross-quad reduce (lanes sharing row m): xor16 then xor32 ----
        best = u64min(best, shfl_xor_u64(best, 16));
        best = u64min(best, shfl_xor_u64(best, 32));
        if (l < 16)
            redw[mt * 16 + m][win] = best;
        __syncthreads();

        // ---- final reduce per row over 8 windows (broadcast b128 reads) ----
        unsigned long long mn;
        {
            const ulonglong2* rp = (const ulonglong2*)&redw[rr_][0];
            ulonglong2 p0 = rp[0], p1 = rp[1], p2 = rp[2], p3 = rp[3];
            mn = u64min(u64min(u64min(p0.x, p0.y), u64min(p1.x, p1.y)),
                        u64min(u64min(p2.x, p2.y), u64min(p3.x, p3.y)));
        }
        const int wb = (int)(mn & 0xffffffffull);
        if (gd == 0)
            out_codes[(size_t)level * N + row0 + rr_] = (float)wb;

        // ---- fp32 residual update in registers (same arithmetic as reference) ----
        {
            const f4v* cp = (const f4v*)(cb_f32 + ((size_t)level * BINS + wb) * D + dbase);
            f4v c = *cp;
            rres[0] -= c[0]; rres[1] -= c[1]; rres[2] -= c[2]; rres[3] -= c[3];
        }
        if (level + 1 < NQ)
            frag_store4(rres, ah, am, al, rr_, g8, half);   // next level's A
    }

    // ---- epilogue: quantized = hidden - residual ----
    {
        const f4v* hp = (const f4v*)(hidden + (size_t)(row0 + rr_) * D + dbase);
        f4v v = *hp;
        f4v q;
        q[0] = v[0] - rres[0]; q[1] = v[1] - rres[1];
        q[2] = v[2] - rres[2]; q[3] = v[3] - rres[3];
        *(f4v*)(out_quant + (size_t)(row0 + rr_) * D + dbase) = q;
    }
}

extern "C" void kernel_launch(void* const* d_in, const int* in_sizes, int n_in,
                              void* d_out, int out_size, void* d_ws, size_t ws_size,
                              hipStream_t stream) {
    const float* hidden    = (const float*)d_in[0];
    const float* codebooks = (const float*)d_in[1];
    float* out = (float*)d_out;
    const int N = in_sizes[0] / D;                 // 8192
    float* out_codes = out;                        // [NQ, N]
    float* out_quant = out + (size_t)NQ * N;       // [N, D]

    char* ws = (char*)d_ws;
    short* cb_hi  = (short*)ws;                    // 512 KB
    short* cb_mid = (short*)(ws +  512 * 1024);    // 512 KB
    short* cb_lo  = (short*)(ws + 1024 * 1024);    // 512 KB
    float* c2     = (float*)(ws + 1536 * 1024);    // 8 KB

    rvq_prep<<<dim3(NQ * 16), 256, 0, stream>>>(codebooks, cb_hi, cb_mid, cb_lo, c2);
    rvq_kernel<<<dim3(N / RPB), THREADS, 0, stream>>>(
        hidden, codebooks, cb_hi, cb_mid, cb_lo, c2, out_codes, out_quant, N);
}

// Round 7
// 202.939 us; speedup vs baseline: 1.0702x; 1.0702x over previous
//
#include <hip/hip_runtime.h>

#define NQ 8
#define BINS 256
#define D 128
#define RPB 32            // rows per block -> grid 256 = minimal B traffic (1 block/CU)
#define THREADS 1024      // 16 waves = 8 bin-windows x 2 row-tiles
#define RSTRIDE 132       // prep staging stride
#define FREG 520          // shorts per frag region (512 + 8 pad -> bank rotation)

typedef short s8v __attribute__((ext_vector_type(8)));   // 8 bf16 in 4 VGPRs
typedef short s4v __attribute__((ext_vector_type(4)));   // 4 bf16 in 2 VGPRs
typedef float f4v __attribute__((ext_vector_type(4)));   // fp32 x4 (subscript = vector extract)

static __device__ __forceinline__ unsigned short bf16_rtne(float x) {
    unsigned u = __float_as_uint(x);
    unsigned r = (u + 0x7fffu + ((u >> 16) & 1u)) >> 16;
    return (unsigned short)r;
}
static __device__ __forceinline__ float bf16_to_f(unsigned short h) {
    return __uint_as_float(((unsigned)h) << 16);
}
struct Split3 { short h, m, l; };
static __device__ __forceinline__ Split3 split3(float x) {
    Split3 s;
    unsigned short hb = bf16_rtne(x);
    float r1 = x - bf16_to_f(hb);
    unsigned short mb = bf16_rtne(r1);
    unsigned short lb = bf16_rtne(r1 - bf16_to_f(mb));
    s.h = (short)hb; s.m = (short)mb; s.l = (short)lb;
    return s;
}
static __device__ __forceinline__ unsigned long long u64min(unsigned long long a, unsigned long long b) {
    return a < b ? a : b;
}
static __device__ __forceinline__ unsigned long long shfl_xor_u64(unsigned long long v, int mask) {
    int lo = (int)(unsigned)(v & 0xffffffffull);
    int hi = (int)(unsigned)(v >> 32);
    lo = __shfl_xor(lo, mask, 64);
    hi = __shfl_xor(hi, mask, 64);
    return ((unsigned long long)(unsigned)hi << 32) | (unsigned)lo;
}

// ---- prep: codebooks fp32 -> bf16 3-way split (swizzled [L][kchunk][bin][8]) + ||c||^2 ----
__global__ __launch_bounds__(256) void rvq_prep(
    const float* __restrict__ cb, short* __restrict__ cb_hi,
    short* __restrict__ cb_mid, short* __restrict__ cb_lo,
    float* __restrict__ c2)
{
    __shared__ float st[16 * RSTRIDE];
    const int L = blockIdx.x >> 4;
    const int o = blockIdx.x & 15;
    const int t = threadIdx.x;

    const float4* src = (const float4*)(cb + ((size_t)L * BINS + o * 16) * D);
    #pragma unroll
    for (int i = 0; i < 2; ++i) {
        int f4 = i * 256 + t;
        int row = f4 >> 5, c4 = f4 & 31;
        float4 v = src[f4];
        float* d = &st[row * RSTRIDE + c4 * 4];
        d[0] = v.x; d[1] = v.y; d[2] = v.z; d[3] = v.w;
    }
    __syncthreads();

    const int bin = t >> 4;
    const int kc  = t & 15;
    const float* p = &st[bin * RSTRIDE + kc * 8];
    s8v h8, m8, l8;
    float s = 0.f;
    #pragma unroll
    for (int j = 0; j < 8; ++j) {
        float x = p[j];
        Split3 sp = split3(x);
        h8[j] = sp.h; m8[j] = sp.m; l8[j] = sp.l;
        s = fmaf(x, x, s);
    }
    int idx = (L * 16 + kc) * BINS + (o * 16 + bin);
    ((s8v*)cb_hi)[idx]  = h8;
    ((s8v*)cb_mid)[idx] = m8;
    ((s8v*)cb_lo)[idx]  = l8;
    s += __shfl_xor(s, 1, 64);
    s += __shfl_xor(s, 2, 64);
    s += __shfl_xor(s, 4, 64);
    s += __shfl_xor(s, 8, 64);
    if (kc == 0) c2[L * BINS + o * 16 + bin] = s;
}

// frag store (unchanged image): thread owns (row rr_, kchunk g8, half); region = mt*4 + ks.
static __device__ __forceinline__ void frag_store4(
    const float* rres, short* ah, short* am, short* al, int rr_, int g8, int half)
{
    s4v h4, m4, l4;
    #pragma unroll
    for (int j = 0; j < 4; ++j) {
        Split3 sp = split3(rres[j]);
        h4[j] = sp.h; m4[j] = sp.m; l4[j] = sp.l;
    }
    int q  = g8 & 3;
    int ks = g8 >> 2;
    int mt = rr_ >> 4;
    int r16 = rr_ & 15;
    int idx16 = q * 16 + ((r16 + 4 * q) & 15);
    int off = (mt * 4 + ks) * FREG + idx16 * 8 + half * 4;
    *(s4v*)&ah[off] = h4;
    *(s4v*)&am[off] = m4;
    *(s4v*)&al[off] = l4;
}

// cb loads for one 16-bin half-window
static __device__ __forceinline__ void issue_cb(
    int lv, int base16, int m, int quad,
    const s8v* __restrict__ bhp, const s8v* __restrict__ bmp, const s8v* __restrict__ blp,
    const float* __restrict__ c2p,
    s8v bh[4], s8v bm[4], s8v bl[4], f4v& c2v)
{
    const int bin = base16 + m;
    #pragma unroll
    for (int ks = 0; ks < 4; ++ks) {
        int idx = (lv * 16 + ks * 4 + quad) * BINS + bin;
        bh[ks] = bhp[idx];
        bm[ks] = bmp[idx];
        bl[ks] = blp[idx];
    }
    c2v = *(const f4v*)(c2p + lv * BINS + base16 + quad * 4);
}

// ---- main: 32 rows/block; wave = (window w>>1, row-tile w&1); residual in registers ----
// waves_per_eu(4,4): we launch exactly 16 waves/CU (4/SIMD); force the register
// allocator to budget 512/4 = 128 VGPRs instead of spilling to hold 8 waves/SIMD
// occupancy that can never materialize.
__global__ __launch_bounds__(THREADS)
__attribute__((amdgpu_waves_per_eu(4, 4)))
void rvq_kernel(
    const float* __restrict__ hidden,     // [N, D]
    const float* __restrict__ cb_f32,     // [NQ, BINS, D]
    const short* __restrict__ cb_hi,
    const short* __restrict__ cb_mid,
    const short* __restrict__ cb_lo,
    const float* __restrict__ c2p,        // [NQ, BINS]
    float* __restrict__ out_codes,        // [NQ, N] as float
    float* __restrict__ out_quant,        // [N, D]
    int N)
{
    __shared__ __align__(16) short ah[8 * FREG];
    __shared__ __align__(16) short am[8 * FREG];
    __shared__ __align__(16) short al[8 * FREG];
    __shared__ __align__(16) unsigned long long redw[RPB][10];  // 80B rows, 16B-aligned

    const int t = threadIdx.x;
    const int w = t >> 6;                 // wave 0..15
    const int l = t & 63;
    const int quad = l >> 4;
    const int m = l & 15;
    const int win  = w >> 1;              // 0..7: 32-bin window
    const int mt   = w & 1;               // which 16-row tile this wave multiplies
    const int woff = win * 32;
    const int row0 = blockIdx.x * RPB;
    const int rr_  = t >> 5;              // owned row 0..31 (for residual/stores)
    const int gd   = t & 31;
    const int g8   = gd >> 1;             // owned k-chunk 0..15
    const int half = gd & 1;
    const int dbase = g8 * 8 + half * 4;  // first owned dim

    // residual in registers: thread owns row rr_, dims [dbase, dbase+4)
    float rres[4];
    {
        const f4v* hp = (const f4v*)(hidden + (size_t)(row0 + rr_) * D + dbase);
        f4v v = *hp;
        rres[0] = v[0]; rres[1] = v[1]; rres[2] = v[2]; rres[3] = v[3];
    }
    frag_store4(rres, ah, am, al, rr_, g8, half);

    const s8v* bhp = (const s8v*)cb_hi;
    const s8v* bmp = (const s8v*)cb_mid;
    const s8v* blp = (const s8v*)cb_lo;

    s8v bh[4], bm[4], bl[4];
    f4v c2v;
    issue_cb(0, woff, m, quad, bhp, bmp, blp, c2p, bh, bm, bl, c2v);  // B(0, nt0) in flight

    for (int level = 0; level < NQ; ++level) {
        __syncthreads();   // frag stores visible

        // ---- residual fragments for MY row-tile only: 12 b128 ----
        s8v rfh[4], rfm[4], rfl[4];
        {
            const int idx16 = quad * 16 + ((m + 4 * quad) & 15);
            #pragma unroll
            for (int ks = 0; ks < 4; ++ks) {
                int off = (mt * 4 + ks) * FREG + idx16 * 8;
                rfh[ks] = *(const s8v*)&ah[off];
                rfm[ks] = *(const s8v*)&am[off];
                rfl[ks] = *(const s8v*)&al[off];
            }
        }

        unsigned long long best = ~0ull;

        #pragma unroll
        for (int nt = 0; nt < 2; ++nt) {
            // swapped operands: D[bin][row]; same scalar products & chain order as
            // the verified kernel -> bit-identical keys
            f4v a0 = {0.f, 0.f, 0.f, 0.f};   // hh
            f4v a1 = {0.f, 0.f, 0.f, 0.f};   // hm + mh
            f4v a2 = {0.f, 0.f, 0.f, 0.f};   // mm + hl + lh
            __builtin_amdgcn_s_setprio(1);
            #pragma unroll
            for (int ks = 0; ks < 4; ++ks) {
                a0 = __builtin_amdgcn_mfma_f32_16x16x32_bf16(bh[ks], rfh[ks], a0, 0, 0, 0);
                a1 = __builtin_amdgcn_mfma_f32_16x16x32_bf16(bm[ks], rfh[ks], a1, 0, 0, 0);
                a1 = __builtin_amdgcn_mfma_f32_16x16x32_bf16(bh[ks], rfm[ks], a1, 0, 0, 0);
                a2 = __builtin_amdgcn_mfma_f32_16x16x32_bf16(bm[ks], rfm[ks], a2, 0, 0, 0);
                a2 = __builtin_amdgcn_mfma_f32_16x16x32_bf16(bl[ks], rfh[ks], a2, 0, 0, 0);
                a2 = __builtin_amdgcn_mfma_f32_16x16x32_bf16(bh[ks], rfl[ks], a2, 0, 0, 0);
            }
            __builtin_amdgcn_s_setprio(0);
            f4v c2cur = c2v;
            const int binbase = woff + nt * 16 + quad * 4;

            // issue next 16-bin half (or next level's first half) after last B use
            if (nt == 0)
                issue_cb(level, woff + 16, m, quad, bhp, bmp, blp, c2p, bh, bm, bl, c2v);
            else if (level + 1 < NQ)
                issue_cb(level + 1, woff, m, quad, bhp, bmp, blp, c2p, bh, bm, bl, c2v);

            #pragma unroll
            for (int i = 0; i < 4; ++i) {
                float dot = a0[i] + (a1[i] + a2[i]);      // same order as verified kernel
                float k = fmaf(-2.f, dot, c2cur[i]);
                unsigned u = __float_as_uint(k);
                u = (u & 0x80000000u) ? ~u : (u | 0x80000000u);
                // pack (key, bin): u64min == min key, ties -> lowest bin
                best = u64min(best, ((unsigned long long)u << 32) | (unsigned)(binbase + i));
            }
        }

        // ---- cross-quad reduce (lanes sharing row m): xor16 then xor32 ----
        best = u64min(best, shfl_xor_u64(best, 16));
        best = u64min(best, shfl_xor_u64(best, 32));
        if (l < 16)
            redw[mt * 16 + m][win] = best;
        __syncthreads();

        // ---- final reduce per row over 8 windows (broadcast b128 reads) ----
        unsigned long long mn;
        {
            const ulonglong2* rp = (const ulonglong2*)&redw[rr_][0];
            ulonglong2 p0 = rp[0], p1 = rp[1], p2 = rp[2], p3 = rp[3];
            mn = u64min(u64min(u64min(p0.x, p0.y), u64min(p1.x, p1.y)),
                        u64min(u64min(p2.x, p2.y), u64min(p3.x, p3.y)));
        }
        const int wb = (int)(mn & 0xffffffffull);
        if (gd == 0)
            out_codes[(size_t)level * N + row0 + rr_] = (float)wb;

        // ---- fp32 residual update in registers (same arithmetic as reference) ----
        {
            const f4v* cp = (const f4v*)(cb_f32 + ((size_t)level * BINS + wb) * D + dbase);
            f4v c = *cp;
            rres[0] -= c[0]; rres[1] -= c[1]; rres[2] -= c[2]; rres[3] -= c[3];
        }
        if (level + 1 < NQ)
            frag_store4(rres, ah, am, al, rr_, g8, half);   // next level's A
    }

    // ---- epilogue: quantized = hidden - residual ----
    {
        const f4v* hp = (const f4v*)(hidden + (size_t)(row0 + rr_) * D + dbase);
        f4v v = *hp;
        f4v q;
        q[0] = v[0] - rres[0]; q[1] = v[1] - rres[1];
        q[2] = v[2] - rres[2]; q[3] = v[3] - rres[3];
        *(f4v*)(out_quant + (size_t)(row0 + rr_) * D + dbase) = q;
    }
}

extern "C" void kernel_launch(void* const* d_in, const int* in_sizes, int n_in,
                              void* d_out, int out_size, void* d_ws, size_t ws_size,
                              hipStream_t stream) {
    const float* hidden    = (const float*)d_in[0];
    const float* codebooks = (const float*)d_in[1];
    float* out = (float*)d_out;
    const int N = in_sizes[0] / D;                 // 8192
    float* out_codes = out;                        // [NQ, N]
    float* out_quant = out + (size_t)NQ * N;       // [N, D]

    char* ws = (char*)d_ws;
    short* cb_hi  = (short*)ws;                    // 512 KB
    short* cb_mid = (short*)(ws +  512 * 1024);    // 512 KB
    short* cb_lo  = (short*)(ws + 1024 * 1024);    // 512 KB
    float* c2     = (float*)(ws + 1536 * 1024);    // 8 KB

    rvq_prep<<<dim3(NQ * 16), 256, 0, stream>>>(codebooks, cb_hi, cb_mid, cb_lo, c2);
    rvq_kernel<<<dim3(N / RPB), THREADS, 0, stream>>>(
        hidden, codebooks, cb_hi, cb_mid, cb_lo, c2, out_codes, out_quant, N);
}

// Round 8
// 102.491 us; speedup vs baseline: 2.1190x; 1.9801x over previous
//
#include <hip/hip_runtime.h>

#define NQ 8
#define BINS 256
#define D 128
#define RPB 32            // rows per block -> grid 256 = minimal B traffic (1 block/CU)
#define THREADS 512       // 8 waves; launch_bounds (512,2) -> VGPR budget 256 (proven in R0)
#define RSTRIDE 132       // prep staging stride
#define FREG 520          // shorts per frag region (512 + 8 pad -> bank rotation)

typedef short s8v __attribute__((ext_vector_type(8)));   // 8 bf16 in 4 VGPRs
typedef float f4v __attribute__((ext_vector_type(4)));   // fp32 x4 (subscript = vector extract)

static __device__ __forceinline__ unsigned short bf16_rtne(float x) {
    unsigned u = __float_as_uint(x);
    unsigned r = (u + 0x7fffu + ((u >> 16) & 1u)) >> 16;
    return (unsigned short)r;
}
static __device__ __forceinline__ float bf16_to_f(unsigned short h) {
    return __uint_as_float(((unsigned)h) << 16);
}
struct Split3 { short h, m, l; };
static __device__ __forceinline__ Split3 split3(float x) {
    Split3 s;
    unsigned short hb = bf16_rtne(x);
    float r1 = x - bf16_to_f(hb);
    unsigned short mb = bf16_rtne(r1);
    unsigned short lb = bf16_rtne(r1 - bf16_to_f(mb));
    s.h = (short)hb; s.m = (short)mb; s.l = (short)lb;
    return s;
}
static __device__ __forceinline__ unsigned long long u64min(unsigned long long a, unsigned long long b) {
    return a < b ? a : b;
}
static __device__ __forceinline__ unsigned long long shfl_xor_u64(unsigned long long v, int mask) {
    int lo = (int)(unsigned)(v & 0xffffffffull);
    int hi = (int)(unsigned)(v >> 32);
    lo = __shfl_xor(lo, mask, 64);
    hi = __shfl_xor(hi, mask, 64);
    return ((unsigned long long)(unsigned)hi << 32) | (unsigned)lo;
}

// ---- prep: codebooks fp32 -> bf16 3-way split (swizzled [L][kchunk][bin][8]) + ||c||^2 ----
__global__ __launch_bounds__(256) void rvq_prep(
    const float* __restrict__ cb, short* __restrict__ cb_hi,
    short* __restrict__ cb_mid, short* __restrict__ cb_lo,
    float* __restrict__ c2)
{
    __shared__ float st[16 * RSTRIDE];
    const int L = blockIdx.x >> 4;
    const int o = blockIdx.x & 15;
    const int t = threadIdx.x;

    const float4* src = (const float4*)(cb + ((size_t)L * BINS + o * 16) * D);
    #pragma unroll
    for (int i = 0; i < 2; ++i) {
        int f4 = i * 256 + t;
        int row = f4 >> 5, c4 = f4 & 31;
        float4 v = src[f4];
        float* d = &st[row * RSTRIDE + c4 * 4];
        d[0] = v.x; d[1] = v.y; d[2] = v.z; d[3] = v.w;
    }
    __syncthreads();

    const int bin = t >> 4;
    const int kc  = t & 15;
    const float* p = &st[bin * RSTRIDE + kc * 8];
    s8v h8, m8, l8;
    float s = 0.f;
    #pragma unroll
    for (int j = 0; j < 8; ++j) {
        float x = p[j];
        Split3 sp = split3(x);
        h8[j] = sp.h; m8[j] = sp.m; l8[j] = sp.l;
        s = fmaf(x, x, s);
    }
    int idx = (L * 16 + kc) * BINS + (o * 16 + bin);
    ((s8v*)cb_hi)[idx]  = h8;
    ((s8v*)cb_mid)[idx] = m8;
    ((s8v*)cb_lo)[idx]  = l8;
    s += __shfl_xor(s, 1, 64);
    s += __shfl_xor(s, 2, 64);
    s += __shfl_xor(s, 4, 64);
    s += __shfl_xor(s, 8, 64);
    if (kc == 0) c2[L * BINS + o * 16 + bin] = s;
}

// frag store (R0-proven image): thread owns (row rr_, kchunk g8); full s8v per split.
static __device__ __forceinline__ void frag_store8(
    const float* rres, short* ah, short* am, short* al, int rr_, int g8)
{
    s8v h8, m8, l8;
    #pragma unroll
    for (int j = 0; j < 8; ++j) {
        Split3 sp = split3(rres[j]);
        h8[j] = sp.h; m8[j] = sp.m; l8[j] = sp.l;
    }
    int q = g8 & 3;
    int reg = (rr_ >> 4) * 4 + (g8 >> 2);          // mt*4 + ks
    int idx16 = q * 16 + (((rr_ & 15) + 4 * q) & 15);
    int off = reg * FREG + idx16 * 8;
    *(s8v*)&ah[off] = h8;
    *(s8v*)&am[off] = m8;
    *(s8v*)&al[off] = l8;
}

// cb loads for one 16-bin half-window
static __device__ __forceinline__ void issue_cb(
    int lv, int base16, int m, int quad,
    const s8v* __restrict__ bhp, const s8v* __restrict__ bmp, const s8v* __restrict__ blp,
    const float* __restrict__ c2p,
    s8v bh[4], s8v bm[4], s8v bl[4], f4v& c2v)
{
    const int bin = base16 + m;
    #pragma unroll
    for (int ks = 0; ks < 4; ++ks) {
        int idx = (lv * 16 + ks * 4 + quad) * BINS + bin;
        bh[ks] = bhp[idx];
        bm[ks] = bmp[idx];
        bl[ks] = blp[idx];
    }
    c2v = *(const f4v*)(c2p + lv * BINS + base16 + quad * 4);
}

// one (mt, nt) MFMA cluster + key fold into best (swapped operands: D[bin][row])
static __device__ __forceinline__ unsigned long long cluster(
    const s8v bh[4], const s8v bm[4], const s8v bl[4],
    const s8v rfh[4], const s8v rfm[4], const s8v rfl[4],
    f4v c2c, int binbase, unsigned long long best)
{
    f4v a0 = {0.f, 0.f, 0.f, 0.f};   // hh
    f4v a1 = {0.f, 0.f, 0.f, 0.f};   // hm + mh
    f4v a2 = {0.f, 0.f, 0.f, 0.f};   // mm + hl + lh
    __builtin_amdgcn_s_setprio(1);
    #pragma unroll
    for (int ks = 0; ks < 4; ++ks) {
        a0 = __builtin_amdgcn_mfma_f32_16x16x32_bf16(bh[ks], rfh[ks], a0, 0, 0, 0);
        a1 = __builtin_amdgcn_mfma_f32_16x16x32_bf16(bm[ks], rfh[ks], a1, 0, 0, 0);
        a1 = __builtin_amdgcn_mfma_f32_16x16x32_bf16(bh[ks], rfm[ks], a1, 0, 0, 0);
        a2 = __builtin_amdgcn_mfma_f32_16x16x32_bf16(bm[ks], rfm[ks], a2, 0, 0, 0);
        a2 = __builtin_amdgcn_mfma_f32_16x16x32_bf16(bl[ks], rfh[ks], a2, 0, 0, 0);
        a2 = __builtin_amdgcn_mfma_f32_16x16x32_bf16(bh[ks], rfl[ks], a2, 0, 0, 0);
    }
    __builtin_amdgcn_s_setprio(0);
    #pragma unroll
    for (int i = 0; i < 4; ++i) {
        float dot = a0[i] + (a1[i] + a2[i]);      // same order as verified kernel
        float k = fmaf(-2.f, dot, c2c[i]);
        unsigned u = __float_as_uint(k);
        u = (u & 0x80000000u) ? ~u : (u | 0x80000000u);
        best = u64min(best, ((unsigned long long)u << 32) | (unsigned)(binbase + i));
    }
    return best;
}

// A-frag load for one row-tile mt (12 x ds_read_b128, proven swizzle pairing)
static __device__ __forceinline__ void load_afrag(
    const short* ah, const short* am, const short* al, int mt, int idx16,
    s8v rfh[4], s8v rfm[4], s8v rfl[4])
{
    #pragma unroll
    for (int ks = 0; ks < 4; ++ks) {
        int off = (mt * 4 + ks) * FREG + idx16 * 8;
        rfh[ks] = *(const s8v*)&ah[off];
        rfm[ks] = *(const s8v*)&am[off];
        rfl[ks] = *(const s8v*)&al[off];
    }
}

// ---- main: 32 rows/block, 8 waves; wave = 32-bin window, mt-outer/nt-inner ----
__global__ __launch_bounds__(THREADS, 2) void rvq_kernel(
    const float* __restrict__ hidden,     // [N, D]
    const float* __restrict__ cb_f32,     // [NQ, BINS, D]
    const short* __restrict__ cb_hi,
    const short* __restrict__ cb_mid,
    const short* __restrict__ cb_lo,
    const float* __restrict__ c2p,        // [NQ, BINS]
    float* __restrict__ out_codes,        // [NQ, N] as float
    float* __restrict__ out_quant,        // [N, D]
    int N)
{
    __shared__ __align__(16) short ah[8 * FREG];
    __shared__ __align__(16) short am[8 * FREG];
    __shared__ __align__(16) short al[8 * FREG];
    __shared__ __align__(16) unsigned long long redw[RPB][10];  // 80B rows, 16B-aligned

    const int t = threadIdx.x;
    const int w = t >> 6;                 // wave 0..7 = 32-bin window
    const int l = t & 63;
    const int quad = l >> 4;
    const int m = l & 15;
    const int woff = w * 32;
    const int row0 = blockIdx.x * RPB;
    const int rr_ = t >> 4;               // owned row 0..31
    const int g8  = t & 15;               // owned k-chunk 0..15
    const int dbase = g8 * 8;             // first owned dim

    // residual + hidden in registers: thread owns row rr_, dims [dbase, dbase+8)
    float rres[8], hreg[8];
    {
        const f4v* hp = (const f4v*)(hidden + (size_t)(row0 + rr_) * D + dbase);
        f4v v0 = hp[0], v1 = hp[1];
        #pragma unroll
        for (int j = 0; j < 4; ++j) { hreg[j] = v0[j]; hreg[4 + j] = v1[j]; }
        #pragma unroll
        for (int j = 0; j < 8; ++j) rres[j] = hreg[j];
    }
    frag_store8(rres, ah, am, al, rr_, g8);

    const s8v* bhp = (const s8v*)cb_hi;
    const s8v* bmp = (const s8v*)cb_mid;
    const s8v* blp = (const s8v*)cb_lo;

    s8v bh0[4], bm0[4], bl0[4];           // nt0 half-window
    s8v bh1[4], bm1[4], bl1[4];           // nt1 half-window
    f4v c20, c21;
    issue_cb(0, woff, m, quad, bhp, bmp, blp, c2p, bh0, bm0, bl0, c20);  // B(0,nt0) in flight

    const int idx16 = quad * 16 + ((m + 4 * quad) & 15);

    for (int level = 0; level < NQ; ++level) {
        __syncthreads();   // frag stores visible; prefetched B(nt0) drained by barrier

        // nt1 issued at level head: latency hides under nt0 compute
        issue_cb(level, woff + 16, m, quad, bhp, bmp, blp, c2p, bh1, bm1, bl1, c21);

        unsigned long long best0 = ~0ull, best1 = ~0ull;
        s8v rfh[4], rfm[4], rfl[4];

        // ---- mt = 0 ----
        load_afrag(ah, am, al, 0, idx16, rfh, rfm, rfl);
        best0 = cluster(bh0, bm0, bl0, rfh, rfm, rfl, c20, woff + quad * 4, best0);
        best0 = cluster(bh1, bm1, bl1, rfh, rfm, rfl, c21, woff + 16 + quad * 4, best0);

        // ---- mt = 1 ----
        load_afrag(ah, am, al, 1, idx16, rfh, rfm, rfl);
        best1 = cluster(bh0, bm0, bl0, rfh, rfm, rfl, c20, woff + quad * 4, best1);
        // bh0 dead -> prefetch next level's nt0 into it (hides L2 under nt1 + tail)
        if (level + 1 < NQ)
            issue_cb(level + 1, woff, m, quad, bhp, bmp, blp, c2p, bh0, bm0, bl0, c20);
        best1 = cluster(bh1, bm1, bl1, rfh, rfm, rfl, c21, woff + 16 + quad * 4, best1);

        // ---- argmin across quads (lanes sharing row m): xor16 then xor32 ----
        best0 = u64min(best0, shfl_xor_u64(best0, 16));
        best0 = u64min(best0, shfl_xor_u64(best0, 32));
        best1 = u64min(best1, shfl_xor_u64(best1, 16));
        best1 = u64min(best1, shfl_xor_u64(best1, 32));
        if (l < 16) {
            redw[m][w]      = best0;
            redw[16 + m][w] = best1;
        }
        __syncthreads();

        // ---- final reduce per row over 8 windows (broadcast b128 reads) ----
        unsigned long long mn;
        {
            const ulonglong2* rp = (const ulonglong2*)&redw[rr_][0];
            ulonglong2 p0 = rp[0], p1 = rp[1], p2 = rp[2], p3 = rp[3];
            mn = u64min(u64min(u64min(p0.x, p0.y), u64min(p1.x, p1.y)),
                        u64min(u64min(p2.x, p2.y), u64min(p3.x, p3.y)));
        }
        const int wb = (int)(mn & 0xffffffffull);
        if (g8 == 0)
            out_codes[(size_t)level * N + row0 + rr_] = (float)wb;

        // ---- fp32 residual update in registers (same arithmetic as reference) ----
        {
            const f4v* cp = (const f4v*)(cb_f32 + ((size_t)level * BINS + wb) * D + dbase);
            f4v c0 = cp[0], c1 = cp[1];
            #pragma unroll
            for (int j = 0; j < 4; ++j) { rres[j] -= c0[j]; rres[4 + j] -= c1[j]; }
        }
        if (level + 1 < NQ)
            frag_store8(rres, ah, am, al, rr_, g8);   // next level's A
    }

    // ---- epilogue: quantized = hidden - residual (hidden kept in registers) ----
    {
        f4v q0, q1;
        #pragma unroll
        for (int j = 0; j < 4; ++j) {
            q0[j] = hreg[j] - rres[j];
            q1[j] = hreg[4 + j] - rres[4 + j];
        }
        f4v* op = (f4v*)(out_quant + (size_t)(row0 + rr_) * D + dbase);
        op[0] = q0; op[1] = q1;
    }
}

extern "C" void kernel_launch(void* const* d_in, const int* in_sizes, int n_in,
                              void* d_out, int out_size, void* d_ws, size_t ws_size,
                              hipStream_t stream) {
    const float* hidden    = (const float*)d_in[0];
    const float* codebooks = (const float*)d_in[1];
    float* out = (float*)d_out;
    const int N = in_sizes[0] / D;                 // 8192
    float* out_codes = out;                        // [NQ, N]
    float* out_quant = out + (size_t)NQ * N;       // [N, D]

    char* ws = (char*)d_ws;
    short* cb_hi  = (short*)ws;                    // 512 KB
    short* cb_mid = (short*)(ws +  512 * 1024);    // 512 KB
    short* cb_lo  = (short*)(ws + 1024 * 1024);    // 512 KB
    float* c2     = (float*)(ws + 1536 * 1024);    // 8 KB

    rvq_prep<<<dim3(NQ * 16), 256, 0, stream>>>(codebooks, cb_hi, cb_mid, cb_lo, c2);
    rvq_kernel<<<dim3(N / RPB), THREADS, 0, stream>>>(
        hidden, codebooks, cb_hi, cb_mid, cb_lo, c2, out_codes, out_quant, N);
}